// Round 3
// baseline (289.267 us; speedup 1.0000x reference)
//
#include <hip/hip_runtime.h>
#include <math.h>

// B=2,T=4096,N=4,DIM=2048 -> 32768 rows of 2048 f32 (256 MiB in, 768 KiB out)
// out = H_pre[32768] ++ H_post[32768] ++ H_res[B,T,4,4] (131072), f32
//
// Fusion: dot(theta, x_tilde) = rstd * sum_c (theta[c]*w[c]) * x[c]
// Round-3 structure: one ROW per 256-thread block iteration.
//   - thread t owns cols {4t..4t+3} and {1024+4t..+3}: 2 float4s/row/thread
//   - 6 folded w*theta vectors live in 48 VGPRs/thread (no LDS in dot loop)
//   - double-buffer x in 16 VGPRs total (round-2 spilled 128-VGPR buffers:
//     WRITE_SIZE 179 MB of scratch; this keeps pressure ~<110)
//   - per-row reduce: 7 partials/thread -> LDS [7][256], one wave sums
//     (16 ds_read_b128 + 2 shuffles), ping-pong slots => 1 barrier/row
#define DIM      2048
#define NROWS    32768
#define EPS_RMS  1e-6f
#define GRID     2048
#define RPB      16          // rows per block (NROWS / GRID)
#define RSTRIDE  260         // LDS row stride (floats); 260*4B is 16B-aligned,
                             // 260 mod 32 = 4 -> 8 scalar-rows hit 8 distinct banks

__device__ __forceinline__ float fast_tanh(float x) {
    // tanh(x) = 1 - 2/(exp(2x)+1); ~1e-7 rel err, exact at +/-inf
    return 1.0f - 2.0f / (__expf(2.0f * x) + 1.0f);
}

__global__ __launch_bounds__(256, 4) void hcmaps_kernel(
    const float* __restrict__ x,
    const float* __restrict__ w,
    const float* __restrict__ alpha_pre_p,
    const float* __restrict__ alpha_post_p,
    const float* __restrict__ alpha_res_p,
    const float* __restrict__ theta_pre,
    const float* __restrict__ theta_post,
    const float* __restrict__ theta_res,   // [4, DIM]
    const float* __restrict__ b_pre,       // [4]
    const float* __restrict__ b_post,      // [4]
    const float* __restrict__ b_res,       // [16] = [i][n]
    float* __restrict__ out)
{
    __shared__ float s_red[2][8][RSTRIDE];   // ping-pong partials [s][t]
    __shared__ float s_bias[7][4];           // bias[s][n]

    const int tid  = threadIdx.x;
    const int lane = tid & 63;
    const int wid  = tid >> 6;

    if (tid < 28) {                          // bias table, read after 1st barrier
        const int s = tid >> 2, n = tid & 3;
        float v;
        if (s == 0)      v = b_pre[n];
        else if (s == 1) v = b_post[n];
        else             v = b_res[(s - 2) * 4 + n];
        s_bias[s][n] = v;
    }

    // ---- fold w*theta into registers (48 VGPRs) ----
    const int c0 = tid * 4;
    const int c1 = DIM / 2 + tid * 4;
    float4 th0[6], th1[6];
    {
        const float4 w0 = *(const float4*)(w + c0);
        const float4 w1 = *(const float4*)(w + c1);
        const float* tv[6] = { theta_pre, theta_post,
                               theta_res,            theta_res + DIM,
                               theta_res + 2 * DIM,  theta_res + 3 * DIM };
#pragma unroll
        for (int v = 0; v < 6; ++v) {
            const float4 a = *(const float4*)(tv[v] + c0);
            const float4 b = *(const float4*)(tv[v] + c1);
            th0[v] = make_float4(a.x * w0.x, a.y * w0.y, a.z * w0.z, a.w * w0.w);
            th1[v] = make_float4(b.x * w1.x, b.y * w1.y, b.z * w1.z, b.w * w1.w);
        }
    }
    const float apre  = alpha_pre_p[0];
    const float apost = alpha_post_p[0];
    const float ares  = alpha_res_p[0];

    const float4* __restrict__ xf4 = (const float4*)x;

    // process row r (iteration k) from (cA,cB); prefetch row r+GRID into (pA,pB)
    auto step = [&](int k, int r, float4 cA, float4 cB, float4& pA, float4& pB) {
        const int rp = (r + GRID < NROWS) ? (r + GRID) : r;   // clamped prefetch
        pA = xf4[(size_t)rp * 512 + tid];
        pB = xf4[(size_t)rp * 512 + 256 + tid];

        float ss = cA.x*cA.x + cA.y*cA.y + cA.z*cA.z + cA.w*cA.w
                 + cB.x*cB.x + cB.y*cB.y + cB.z*cB.z + cB.w*cB.w;
        float d[6];
#pragma unroll
        for (int v = 0; v < 6; ++v) {
            d[v] = th0[v].x*cA.x + th0[v].y*cA.y + th0[v].z*cA.z + th0[v].w*cA.w
                 + th1[v].x*cB.x + th1[v].y*cB.y + th1[v].z*cB.z + th1[v].w*cB.w;
        }

        const int pp = k & 1;
        float* wr = &s_red[pp][0][tid];      // lanes write consecutive floats: 2-way, free
#pragma unroll
        for (int v = 0; v < 6; ++v) wr[v * RSTRIDE] = d[v];
        wr[6 * RSTRIDE] = ss;

        __syncthreads();

        if (wid == (k & 3) && lane < 32) {   // round-robin epilogue wave
            const int s = lane & 7, q = lane >> 3;        // s=7 row is dummy
            const float* rd = &s_red[pp][0][0] + s * RSTRIDE + q * 64;
            float4 acc = make_float4(0.f, 0.f, 0.f, 0.f);
#pragma unroll
            for (int c = 0; c < 16; ++c) {
                const float4 v4 = *(const float4*)(rd + c * 4);
                acc.x += v4.x; acc.y += v4.y; acc.z += v4.z; acc.w += v4.w;
            }
            float P = (acc.x + acc.y) + (acc.z + acc.w);
            P += __shfl_xor(P, 8);           // combine q pairs (s preserved)
            P += __shfl_xor(P, 16);
            const float ssT = __shfl(P, 6);  // broadcast sum(x^2) total
            if (lane < 6) {
                const float rstd = rsqrtf(ssT * (1.0f / DIM) + EPS_RMS);
                const int n = r & 3, rbt = r >> 2;
                const float alpha = (s == 0) ? apre : ((s == 1) ? apost : ares);
                const float val = alpha * fast_tanh(P * rstd) + s_bias[s][n];
                const int addr = (s == 0) ? r
                               : ((s == 1) ? (NROWS + r)
                                           : (2 * NROWS + rbt * 16 + (s - 2) * 4 + n));
                out[addr] = val;
            }
        }
    };

    const int r0 = blockIdx.x;
    float4 A0 = xf4[(size_t)r0 * 512 + tid];
    float4 B0 = xf4[(size_t)r0 * 512 + 256 + tid];
    float4 A1, B1;

    for (int k = 0; k < RPB; k += 2) {       // named bufs: no runtime indexing
        step(k,     r0 + k * GRID,       A0, B0, A1, B1);
        step(k + 1, r0 + (k + 1) * GRID, A1, B1, A0, B0);
    }
}

extern "C" void kernel_launch(void* const* d_in, const int* in_sizes, int n_in,
                              void* d_out, int out_size, void* d_ws, size_t ws_size,
                              hipStream_t stream) {
    const float* x          = (const float*)d_in[0];
    const float* rms_weight = (const float*)d_in[1];
    const float* alpha_pre  = (const float*)d_in[2];
    const float* alpha_post = (const float*)d_in[3];
    const float* alpha_res  = (const float*)d_in[4];
    const float* theta_pre  = (const float*)d_in[5];
    const float* theta_post = (const float*)d_in[6];
    const float* theta_res  = (const float*)d_in[7];
    const float* b_pre      = (const float*)d_in[8];
    const float* b_post     = (const float*)d_in[9];
    const float* b_res      = (const float*)d_in[10];
    float* out = (float*)d_out;

    dim3 grid(GRID);
    dim3 block(256);
    hipLaunchKernelGGL(hcmaps_kernel, grid, block, 0, stream,
                       x, rms_weight, alpha_pre, alpha_post, alpha_res,
                       theta_pre, theta_post, theta_res,
                       b_pre, b_post, b_res, out);
}

// Round 4
// 83.327 us; speedup vs baseline: 3.4715x; 3.4715x over previous
//
#include <hip/hip_runtime.h>
#include <math.h>

// B=2,T=4096,N=4,DIM=2048 -> 32768 rows of 2048 f32 (256 MiB in, 768 KiB out)
// out = H_pre[32768] ++ H_post[32768] ++ H_res[B,T,4,4] (131072), f32
//
// Fusion: dot(theta, x_tilde) = rstd * sum_c (theta[c]*w[c]) * x[c]
// -> single pass over x: sum(x^2) + 6 folded dots, then tanh epilogue.
//
// Round-4 structure (latency-bound fix via occupancy, not buffering):
//   - 1024-thread blocks (16 waves), theta in 48 KiB LDS -> 2 blocks/CU
//     = 32 waves/CU (round 1: 12 cap / 3.4 measured)
//   - one row per wave; 2 rows per wave total; ~50 VGPR live (rounds 2/3
//     spilled 128+ VGPR of buffered state: WRITE_SIZE 164-179 MB scratch)
//   - no lambdas / pointer arrays / runtime-indexed register arrays
#define DIM     2048
#define NROWS   32768
#define EPS_RMS 1e-6f
#define NTH     6
#define BLK     1024
#define GRIDN   1024     // 16384 waves; rows gw and gw+16384

__device__ __forceinline__ float fast_tanh(float x) {
    // tanh(x) = 1 - 2/(exp(2x)+1); ~1e-7 rel err, exact at +/-inf
    return 1.0f - 2.0f / (__expf(2.0f * x) + 1.0f);
}

#define DOT4(t, a) ((t).x*(a).x + (t).y*(a).y + (t).z*(a).z + (t).w*(a).w)

__global__ __launch_bounds__(BLK, 8) void hcmaps_kernel(
    const float* __restrict__ x,
    const float* __restrict__ w,
    const float* __restrict__ alpha_pre_p,
    const float* __restrict__ alpha_post_p,
    const float* __restrict__ alpha_res_p,
    const float* __restrict__ theta_pre,
    const float* __restrict__ theta_post,
    const float* __restrict__ theta_res,   // [4, DIM]
    const float* __restrict__ b_pre,       // [4]
    const float* __restrict__ b_post,      // [4]
    const float* __restrict__ b_res,       // [16] = [i][n]
    float* __restrict__ out)
{
    __shared__ float s_wt[NTH * DIM];      // 48 KiB: w*theta, 6 vectors

    const int tid  = threadIdx.x;
    const int lane = tid & 63;
    const int wid  = tid >> 6;
    const int gw   = blockIdx.x * 16 + wid;      // wave id = first row
    const int r0   = gw;
    const int r1   = gw + 16384;

    const float4* __restrict__ xf4 = (const float4*)x;

    // ---- issue row-0 loads FIRST (HBM latency hides under theta fill) ----
    float4 xv[8];
    {
        const float4* xr = xf4 + (size_t)r0 * 512;
#pragma unroll
        for (int j = 0; j < 8; ++j) xv[j] = xr[j * 64 + lane];
    }

    // ---- fold w*theta into LDS (3 float4 per thread, no pointer array) ----
#pragma unroll
    for (int it = 0; it < 3; ++it) {
        const int q  = tid + it * BLK;           // 0..3071
        const int v  = q >> 9;                   // theta index 0..5
        const int cf = q & 511;                  // float4 col
        const float* tb = (v == 0) ? theta_pre
                        : (v == 1) ? theta_post
                                   : (theta_res + (v - 2) * DIM);
        const float4 wv = ((const float4*)w)[cf];
        const float4 t4 = ((const float4*)tb)[cf];
        ((float4*)s_wt)[q] =
            make_float4(wv.x * t4.x, wv.y * t4.y, wv.z * t4.z, wv.w * t4.w);
    }

    // per-wave constants (uniform scalar loads / tiny divergent loads)
    const float apre  = alpha_pre_p[0];
    const float apost = alpha_post_p[0];
    const float ares  = alpha_res_p[0];
    const int   n     = gw & 3;                  // same for r0 and r1
    float bias = 0.f, alpha = 0.f;
    if (lane < 6) {
        alpha = (lane == 0) ? apre : (lane == 1) ? apost : ares;
        bias  = (lane == 0) ? b_pre[n]
              : (lane == 1) ? b_post[n]
                            : b_res[(lane - 2) * 4 + n];
    }

    __syncthreads();

    // ================= row 0 =================
    float ss = 0.f, d0 = 0.f, d1 = 0.f, d2 = 0.f, d3 = 0.f, d4 = 0.f, d5 = 0.f;
#pragma unroll
    for (int j = 0; j < 8; ++j) {
        const float4 a = xv[j];
        const float* tb = s_wt + j * 256 + lane * 4;   // + v*DIM via imm offset
        ss += DOT4(a, a);
        float4 t;
        t = *(const float4*)(tb + 0 * DIM); d0 += DOT4(t, a);
        t = *(const float4*)(tb + 1 * DIM); d1 += DOT4(t, a);
        t = *(const float4*)(tb + 2 * DIM); d2 += DOT4(t, a);
        t = *(const float4*)(tb + 3 * DIM); d3 += DOT4(t, a);
        t = *(const float4*)(tb + 4 * DIM); d4 += DOT4(t, a);
        t = *(const float4*)(tb + 5 * DIM); d5 += DOT4(t, a);
    }

    // ---- issue row-1 loads before the butterfly (xv regs now dead) ----
    float4 yv[8];
    {
        const float4* xr = xf4 + (size_t)r1 * 512;
#pragma unroll
        for (int j = 0; j < 8; ++j) yv[j] = xr[j * 64 + lane];
    }

#pragma unroll
    for (int off = 1; off < 64; off <<= 1) {
        ss += __shfl_xor(ss, off);
        d0 += __shfl_xor(d0, off);
        d1 += __shfl_xor(d1, off);
        d2 += __shfl_xor(d2, off);
        d3 += __shfl_xor(d3, off);
        d4 += __shfl_xor(d4, off);
        d5 += __shfl_xor(d5, off);
    }
    if (lane < 6) {
        const float dv = (lane == 0) ? d0 : (lane == 1) ? d1 : (lane == 2) ? d2
                       : (lane == 3) ? d3 : (lane == 4) ? d4 : d5;
        const float rstd = rsqrtf(ss * (1.0f / DIM) + EPS_RMS);
        const float val  = alpha * fast_tanh(dv * rstd) + bias;
        int addr;
        if (lane == 0)      addr = r0;
        else if (lane == 1) addr = NROWS + r0;
        else                addr = 2 * NROWS + (r0 >> 2) * 16 + (lane - 2) * 4 + n;
        out[addr] = val;
    }

    // ================= row 1 =================
    ss = 0.f; d0 = 0.f; d1 = 0.f; d2 = 0.f; d3 = 0.f; d4 = 0.f; d5 = 0.f;
#pragma unroll
    for (int j = 0; j < 8; ++j) {
        const float4 a = yv[j];
        const float* tb = s_wt + j * 256 + lane * 4;
        ss += DOT4(a, a);
        float4 t;
        t = *(const float4*)(tb + 0 * DIM); d0 += DOT4(t, a);
        t = *(const float4*)(tb + 1 * DIM); d1 += DOT4(t, a);
        t = *(const float4*)(tb + 2 * DIM); d2 += DOT4(t, a);
        t = *(const float4*)(tb + 3 * DIM); d3 += DOT4(t, a);
        t = *(const float4*)(tb + 4 * DIM); d4 += DOT4(t, a);
        t = *(const float4*)(tb + 5 * DIM); d5 += DOT4(t, a);
    }
#pragma unroll
    for (int off = 1; off < 64; off <<= 1) {
        ss += __shfl_xor(ss, off);
        d0 += __shfl_xor(d0, off);
        d1 += __shfl_xor(d1, off);
        d2 += __shfl_xor(d2, off);
        d3 += __shfl_xor(d3, off);
        d4 += __shfl_xor(d4, off);
        d5 += __shfl_xor(d5, off);
    }
    if (lane < 6) {
        const float dv = (lane == 0) ? d0 : (lane == 1) ? d1 : (lane == 2) ? d2
                       : (lane == 3) ? d3 : (lane == 4) ? d4 : d5;
        const float rstd = rsqrtf(ss * (1.0f / DIM) + EPS_RMS);
        const float val  = alpha * fast_tanh(dv * rstd) + bias;
        int addr;
        if (lane == 0)      addr = r1;
        else if (lane == 1) addr = NROWS + r1;
        else                addr = 2 * NROWS + (r1 >> 2) * 16 + (lane - 2) * 4 + n;
        out[addr] = val;
    }
}

extern "C" void kernel_launch(void* const* d_in, const int* in_sizes, int n_in,
                              void* d_out, int out_size, void* d_ws, size_t ws_size,
                              hipStream_t stream) {
    const float* x          = (const float*)d_in[0];
    const float* rms_weight = (const float*)d_in[1];
    const float* alpha_pre  = (const float*)d_in[2];
    const float* alpha_post = (const float*)d_in[3];
    const float* alpha_res  = (const float*)d_in[4];
    const float* theta_pre  = (const float*)d_in[5];
    const float* theta_post = (const float*)d_in[6];
    const float* theta_res  = (const float*)d_in[7];
    const float* b_pre      = (const float*)d_in[8];
    const float* b_post     = (const float*)d_in[9];
    const float* b_res      = (const float*)d_in[10];
    float* out = (float*)d_out;

    dim3 grid(GRIDN);
    dim3 block(BLK);
    hipLaunchKernelGGL(hcmaps_kernel, grid, block, 0, stream,
                       x, rms_weight, alpha_pre, alpha_post, alpha_res,
                       theta_pre, theta_post, theta_res,
                       b_pre, b_post, b_res, out);
}

// Round 5
// 46.562 us; speedup vs baseline: 6.2125x; 1.7896x over previous
//
#include <hip/hip_runtime.h>
#include <math.h>

// B=2,T=4096,N=4,DIM=2048 -> 32768 rows of 2048 f32 (256 MiB in, 768 KiB out)
// out = H_pre[32768] ++ H_post[32768] ++ H_res[B,T,4,4] (131072), f32
//
// Fusion: dot(theta, x_tilde) = rstd * sum_c (theta[c]*w[c]) * x[c]
// -> single pass over x: sum(x^2) + 6 folded dots, then tanh epilogue.
//
// Round-5 (DS-pipe reduction; round 4 = 83 us with modeled ~44 us/CU DS busy):
//   - one wave computes TWO rows (gw, gw+16384): each ds_read_b128 of w*theta
//     feeds both rows' FMAs -> theta LDS traffic halved (48 -> 24 b128/row)
//   - x processed in two 1024-col chunks: only 32 VGPR of x live at a time
//     (rounds 2/3 lesson: big register buffers spill -> scratch traffic)
//   - wave reduction: 4x DPP row_ror adds (VALU) + 2 shuffles per chain
//     instead of 6 ds_bpermute: shuffle DS ops 84 -> 28 per row-pair
//   - 1024-thread blocks, 48 KiB LDS, ~80 VGPR -> ~24 waves/CU resident
#define DIM     2048
#define NROWS   32768
#define EPS_RMS 1e-6f
#define NTH     6
#define BLK     1024
#define GRIDN   1024     // 16384 waves; each owns rows gw and gw+16384

__device__ __forceinline__ float fast_tanh(float x) {
    // tanh(x) = 1 - 2/(exp(2x)+1); ~1e-7 rel err, exact at +/-inf
    return 1.0f - 2.0f / (__expf(2.0f * x) + 1.0f);
}

#define DOT4(t, a) ((t).x*(a).x + (t).y*(a).y + (t).z*(a).z + (t).w*(a).w)

// v += row_ror:<k>(v)  (within 16-lane DPP rows; VALU pipe, no DS traffic)
#define ROR_ADD(v, CTRL)                                                      \
    do {                                                                      \
        int _iv = __float_as_int(v);                                          \
        int _r  = __builtin_amdgcn_update_dpp(_iv, _iv, (CTRL), 0xF, 0xF, false); \
        (v) += __int_as_float(_r);                                            \
    } while (0)

// full 64-lane sum, result broadcast to all lanes:
// 4 DPP rotate-adds (lanes hold 16-group sum) + xor16 + xor32
#define WAVE_SUM(v)                                                           \
    do {                                                                      \
        ROR_ADD(v, 0x121);  /* row_ror:1 */                                   \
        ROR_ADD(v, 0x122);  /* row_ror:2 */                                   \
        ROR_ADD(v, 0x124);  /* row_ror:4 */                                   \
        ROR_ADD(v, 0x128);  /* row_ror:8 */                                   \
        (v) += __shfl_xor((v), 16);                                           \
        (v) += __shfl_xor((v), 32);                                           \
    } while (0)

__global__ __launch_bounds__(BLK, 4) void hcmaps_kernel(
    const float* __restrict__ x,
    const float* __restrict__ w,
    const float* __restrict__ alpha_pre_p,
    const float* __restrict__ alpha_post_p,
    const float* __restrict__ alpha_res_p,
    const float* __restrict__ theta_pre,
    const float* __restrict__ theta_post,
    const float* __restrict__ theta_res,   // [4, DIM]
    const float* __restrict__ b_pre,       // [4]
    const float* __restrict__ b_post,      // [4]
    const float* __restrict__ b_res,       // [16] = [i][n]
    float* __restrict__ out)
{
    __shared__ float s_wt[NTH * DIM];      // 48 KiB: w*theta, 6 vectors

    const int tid  = threadIdx.x;
    const int lane = tid & 63;
    const int wid  = tid >> 6;
    const int gw   = blockIdx.x * 16 + wid;      // 0..16383
    const int r0   = gw;
    const int r1   = gw + 16384;

    const float4* __restrict__ xf4 = (const float4*)x;

    // ---- issue chunk-0 loads for BOTH rows first (hide under theta fill) ----
    float4 xa[4], xb[4];
    {
        const float4* ra = xf4 + (size_t)r0 * 512;
        const float4* rb = xf4 + (size_t)r1 * 512;
#pragma unroll
        for (int j = 0; j < 4; ++j) {
            xa[j] = ra[j * 64 + lane];
            xb[j] = rb[j * 64 + lane];
        }
    }

    // ---- fold w*theta into LDS (3 float4 per thread) ----
#pragma unroll
    for (int it = 0; it < 3; ++it) {
        const int q  = tid + it * BLK;           // 0..3071
        const int v  = q >> 9;                   // theta index 0..5
        const int cf = q & 511;                  // float4 col
        const float* tb = (v == 0) ? theta_pre
                        : (v == 1) ? theta_post
                                   : (theta_res + (v - 2) * DIM);
        const float4 wv = ((const float4*)w)[cf];
        const float4 t4 = ((const float4*)tb)[cf];
        ((float4*)s_wt)[q] =
            make_float4(wv.x * t4.x, wv.y * t4.y, wv.z * t4.z, wv.w * t4.w);
    }

    const float apre  = alpha_pre_p[0];
    const float apost = alpha_post_p[0];
    const float ares  = alpha_res_p[0];
    const int   n     = gw & 3;                  // (gw+16384)&3 == gw&3
    // per-lane epilogue constants: s = lane&7 selects output kind
    const int   s     = lane & 7;
    float bias = 0.f, alpha = 0.f;
    if (s < 6) {
        alpha = (s == 0) ? apre : (s == 1) ? apost : ares;
        bias  = (s == 0) ? b_pre[n]
              : (s == 1) ? b_post[n]
                         : b_res[(s - 2) * 4 + n];
    }

    __syncthreads();

    float ssa = 0.f, ssb = 0.f;
    float da0 = 0.f, da1 = 0.f, da2 = 0.f, da3 = 0.f, da4 = 0.f, da5 = 0.f;
    float db0 = 0.f, db1 = 0.f, db2 = 0.f, db3 = 0.f, db4 = 0.f, db5 = 0.f;

#pragma unroll
    for (int chunk = 0; chunk < 2; ++chunk) {
        if (chunk == 1) {                        // chunk-1 loads (TLP hides latency)
            const float4* ra = xf4 + (size_t)r0 * 512 + 256;
            const float4* rb = xf4 + (size_t)r1 * 512 + 256;
#pragma unroll
            for (int j = 0; j < 4; ++j) {
                xa[j] = ra[j * 64 + lane];
                xb[j] = rb[j * 64 + lane];
            }
        }
#pragma unroll
        for (int j = 0; j < 4; ++j) {
            const float4 a = xa[j];
            const float4 b = xb[j];
            const float* tb = s_wt + chunk * 1024 + j * 256 + lane * 4;
            ssa += DOT4(a, a);
            ssb += DOT4(b, b);
            float4 t;
            t = *(const float4*)(tb + 0 * DIM); da0 += DOT4(t, a); db0 += DOT4(t, b);
            t = *(const float4*)(tb + 1 * DIM); da1 += DOT4(t, a); db1 += DOT4(t, b);
            t = *(const float4*)(tb + 2 * DIM); da2 += DOT4(t, a); db2 += DOT4(t, b);
            t = *(const float4*)(tb + 3 * DIM); da3 += DOT4(t, a); db3 += DOT4(t, b);
            t = *(const float4*)(tb + 4 * DIM); da4 += DOT4(t, a); db4 += DOT4(t, b);
            t = *(const float4*)(tb + 5 * DIM); da5 += DOT4(t, a); db5 += DOT4(t, b);
        }
    }

    // ---- 14 wave sums: DPP rotates (VALU) + 2 shuffles each ----
    WAVE_SUM(ssa); WAVE_SUM(ssb);
    WAVE_SUM(da0); WAVE_SUM(da1); WAVE_SUM(da2);
    WAVE_SUM(da3); WAVE_SUM(da4); WAVE_SUM(da5);
    WAVE_SUM(db0); WAVE_SUM(db1); WAVE_SUM(db2);
    WAVE_SUM(db3); WAVE_SUM(db4); WAVE_SUM(db5);

    // ---- epilogue: lanes 0..5 write row r0, lanes 8..13 write row r1 ----
    const bool rowB = lane >= 8;
    if (s < 6 && lane < 14) {
        const float ss = rowB ? ssb : ssa;
        const float c0 = rowB ? db0 : da0;
        const float c1 = rowB ? db1 : da1;
        const float c2 = rowB ? db2 : da2;
        const float c3 = rowB ? db3 : da3;
        const float c4 = rowB ? db4 : da4;
        const float c5 = rowB ? db5 : da5;
        const float dv = (s == 0) ? c0 : (s == 1) ? c1 : (s == 2) ? c2
                       : (s == 3) ? c3 : (s == 4) ? c4 : c5;
        const int   r  = rowB ? r1 : r0;
        const float rstd = rsqrtf(ss * (1.0f / DIM) + EPS_RMS);
        const float val  = alpha * fast_tanh(dv * rstd) + bias;
        int addr;
        if (s == 0)      addr = r;
        else if (s == 1) addr = NROWS + r;
        else             addr = 2 * NROWS + (r >> 2) * 16 + (s - 2) * 4 + n;
        out[addr] = val;
    }
}

extern "C" void kernel_launch(void* const* d_in, const int* in_sizes, int n_in,
                              void* d_out, int out_size, void* d_ws, size_t ws_size,
                              hipStream_t stream) {
    const float* x          = (const float*)d_in[0];
    const float* rms_weight = (const float*)d_in[1];
    const float* alpha_pre  = (const float*)d_in[2];
    const float* alpha_post = (const float*)d_in[3];
    const float* alpha_res  = (const float*)d_in[4];
    const float* theta_pre  = (const float*)d_in[5];
    const float* theta_post = (const float*)d_in[6];
    const float* theta_res  = (const float*)d_in[7];
    const float* b_pre      = (const float*)d_in[8];
    const float* b_post     = (const float*)d_in[9];
    const float* b_res      = (const float*)d_in[10];
    float* out = (float*)d_out;

    dim3 grid(GRIDN);
    dim3 block(BLK);
    hipLaunchKernelGGL(hcmaps_kernel, grid, block, 0, stream,
                       x, rms_weight, alpha_pre, alpha_post, alpha_res,
                       theta_pre, theta_post, theta_res,
                       b_pre, b_post, b_res, out);
}